// Round 10
// baseline (44.211 us; speedup 1.0000x reference)
//
#include <hip/hip_runtime.h>

// NoiseLearnModule: out = x + where(0<=bin<16, eps * sigmoid(params[f,bin]) * 0.1, 0)
// bin = searchsorted(bins[f], x, side='right') - 1
// x,eps [65536,256] f32; bins [256,17] f32; params [256*16] f32.
//
// R10 = R9 (zero-LDS, 1 feature/thread, fused cndmask scan+select) + two fixes
// for the measured failure mode (VGPR=32: compiler rematerializes the 33-float
// table from memory every iteration instead of keeping it in registers):
//  1. PIN ed[]/sg[] with asm volatile("" : "+v") — values become opaque, the
//     allocator must hold them in VGPRs for the whole kernel (anti-remat fence).
//  2. Software-pipeline U=4: prefetch next iteration's 8 loads before
//     computing the current one — ~280 VALU cycles cover the load latency.

#define NFEAT 256
#define NBINS 16
#define NEDGE 17
#define NOISE_SCALE 0.1f

__global__ __launch_bounds__(256, 4) void noise_learn_kernel(
    const float* __restrict__ x,
    const float* __restrict__ bins,
    const float* __restrict__ eps,
    const float* __restrict__ params,
    float* __restrict__ out,
    int total)
{
    const int t = threadIdx.x;               // == feature id

    // Prologue: tables -> registers.
    float ed[NEDGE];
    #pragma unroll
    for (int i = 0; i < NEDGE; ++i)
        ed[i] = bins[t * NEDGE + i];

    float sg[NBINS];                         // pre-scaled: 0.1 * sigmoid(p)
    #pragma unroll
    for (int k = 0; k < NBINS; ++k)
        sg[k] = NOISE_SCALE / (1.0f + __expf(-params[t * NBINS + k]));

    // Anti-rematerialization pins: each value is now opaque -> must stay in a
    // VGPR; the compiler can no longer re-load it from bins/params per iter.
    #pragma unroll
    for (int i = 0; i < NEDGE; ++i) asm volatile("" : "+v"(ed[i]));
    #pragma unroll
    for (int k = 0; k < NBINS; ++k) asm volatile("" : "+v"(sg[k]));

    const int n = gridDim.x * 256;           // multiple of 256 -> feature invariant
    const int gid = blockIdx.x * 256 + t;

    // total = 16,777,216 = (2048*256) * 4 * 8 -> exactly 8 guard-free iters.
    int base = gid;

    // Load iteration 0.
    float xA = x[base], xB = x[base + n], xC = x[base + 2 * n], xD = x[base + 3 * n];
    float pA = eps[base], pB = eps[base + n], pC = eps[base + 2 * n], pD = eps[base + 3 * n];

    // Pipelined main loop: prefetch iter i+1, compute/store iter i.
    while (base + 7 * n < total) {           // a full next iteration exists
        const int nb = base + 4 * n;

        // Prefetch next iteration (8 independent coalesced loads in flight).
        const float nxA = x[nb], nxB = x[nb + n], nxC = x[nb + 2 * n], nxD = x[nb + 3 * n];
        const float npA = eps[nb], npB = eps[nb + n], npC = eps[nb + 2 * n], npD = eps[nb + 3 * n];

        // Compute current iteration from held registers.
        float sA = sg[0], sB = sg[0], sC = sg[0], sD = sg[0];
        #pragma unroll
        for (int i = 1; i < NBINS; ++i) {
            sA = (ed[i] <= xA) ? sg[i] : sA;
            sB = (ed[i] <= xB) ? sg[i] : sB;
            sC = (ed[i] <= xC) ? sg[i] : sC;
            sD = (ed[i] <= xD) ? sg[i] : sD;
        }
        const float vA = (ed[0] <= xA && xA < ed[NEDGE - 1]) ? sA : 0.0f;
        const float vB = (ed[0] <= xB && xB < ed[NEDGE - 1]) ? sB : 0.0f;
        const float vC = (ed[0] <= xC && xC < ed[NEDGE - 1]) ? sC : 0.0f;
        const float vD = (ed[0] <= xD && xD < ed[NEDGE - 1]) ? sD : 0.0f;

        out[base]         = fmaf(pA, vA, xA);
        out[base + n]     = fmaf(pB, vB, xB);
        out[base + 2 * n] = fmaf(pC, vC, xC);
        out[base + 3 * n] = fmaf(pD, vD, xD);

        // Rotate pipeline registers.
        xA = nxA; xB = nxB; xC = nxC; xD = nxD;
        pA = npA; pB = npB; pC = npC; pD = npD;
        base = nb;
    }

    // Epilogue: last iteration (already loaded).
    {
        float sA = sg[0], sB = sg[0], sC = sg[0], sD = sg[0];
        #pragma unroll
        for (int i = 1; i < NBINS; ++i) {
            sA = (ed[i] <= xA) ? sg[i] : sA;
            sB = (ed[i] <= xB) ? sg[i] : sB;
            sC = (ed[i] <= xC) ? sg[i] : sC;
            sD = (ed[i] <= xD) ? sg[i] : sD;
        }
        const float vA = (ed[0] <= xA && xA < ed[NEDGE - 1]) ? sA : 0.0f;
        const float vB = (ed[0] <= xB && xB < ed[NEDGE - 1]) ? sB : 0.0f;
        const float vC = (ed[0] <= xC && xC < ed[NEDGE - 1]) ? sC : 0.0f;
        const float vD = (ed[0] <= xD && xD < ed[NEDGE - 1]) ? sD : 0.0f;

        out[base]         = fmaf(pA, vA, xA);
        out[base + n]     = fmaf(pB, vB, xB);
        out[base + 2 * n] = fmaf(pC, vC, xC);
        out[base + 3 * n] = fmaf(pD, vD, xD);
    }
}

extern "C" void kernel_launch(void* const* d_in, const int* in_sizes, int n_in,
                              void* d_out, int out_size, void* d_ws, size_t ws_size,
                              hipStream_t stream) {
    const float* x      = (const float*)d_in[0];
    const float* bins   = (const float*)d_in[1];
    const float* eps    = (const float*)d_in[2];
    const float* params = (const float*)d_in[3];
    float* out = (float*)d_out;

    dim3 block(256);
    dim3 grid(2048);   // zero LDS; 8 pipelined iterations of U=4, no tail
    noise_learn_kernel<<<grid, block, 0, stream>>>(x, bins, eps, params, out, out_size);
}